// Round 15
// baseline (29.897 us; speedup 1.0000x reference)
//
#include <hip/hip_runtime.h>

// Bidirectional Chamfer loss, fused:
//   out = 1e-4 * ( sum_n min_m |shape[b,n]-skel[b,m]|^2
//                + sum_m min_n |skel[b,m]-shape[b,n]|^2 )
//
// R15: R14 (QPT=16 @ 8 waves/CU) was null vs R7 (QPT=8 @ 16 waves/CU) —
// LDS-demand relief and occupancy loss cancelled. The untested corner is
// QPT=16 @ 16 waves/CU, which requires partials = waves*64*QPT = 4.2M
// floats (16.8 MB). BIG path (ws-gated): 1024 blocks x 256thr, CH=32,
// dir1 [b][64][8192] + dir2 [b][256][2048], reduce 768 blocks.
// SMALL fallback = R14 verbatim (proven 24.19) if ws_size < ~16.8 MB.

#define QPT    16
#define BIGF   3.4e38f

// BIG layout (floats): dir1 2,097,152 @0; dir2 2,097,152 @P2B; psum @PSB.
#define P2B      2097152
#define PSB      4194304
#define RB_BIG   768
// SMALL layout (= R14): dir1 1,048,576 @0; dir2 @P2S; psum @PSS.
#define P2S      1048576
#define PSS      2097152
#define RB_SMALL 640

// ---------------- BIG path: QPT=16, 4 blocks/CU (16 waves/CU) -------------
__global__ __launch_bounds__(256, 4) void chamfer_big(
    const float* __restrict__ shape, const float* __restrict__ skel,
    float* __restrict__ pw)
{
    const int b = blockIdx.y, tid = threadIdx.x;

    const float* qsrc; const float* ssrc; float* pbase;
    int q0, qstride, lbase, si;
    int x = blockIdx.x;
    if (x < 128) {                      // dir1: 2 qb x 64 ch (CH=32)
        const int qb = x >> 6, ch = x & 63;
        pbase   = pw + ((size_t)b * 64 + ch) * 8192;
        q0      = qb * 4096 + tid; qstride = 256;
        lbase   = 0;  si = tid;
        ssrc    = skel + ((size_t)b * 2048 + ch * 32) * 3;
        qsrc    = shape + (size_t)b * 8192 * 3;
    } else {                            // dir2: half-blocks own chunks (CH=32)
        const int z = x - 128, half = tid >> 7;
        const int ch = 2 * z + half;    // 0..255
        pbase   = pw + P2B + ((size_t)b * 256 + ch) * 2048;
        q0      = tid & 127; qstride = 128;
        lbase   = half * 32;  si = tid & 127;
        ssrc    = shape + ((size_t)b * 8192 + z * 64 + half * 32) * 3;
        qsrc    = skel + (size_t)b * 2048 * 3;
    }

    __shared__ float4 lds[64];

    // Stage 32 targets per (half-)group as (x, y, z, |t|^2).
    if (si < 32) {
        float tx = ssrc[si * 3 + 0], ty = ssrc[si * 3 + 1], tz = ssrc[si * 3 + 2];
        lds[lbase + si] = make_float4(tx, ty, tz, tx * tx + ty * ty + tz * tz);
    }

    // My 16 query points: precompute -2q and |q|^2.
    const float* qp = qsrc + (size_t)q0 * 3;
    const int qs3 = qstride * 3;
    float nqx[QPT], nqy[QPT], nqz[QPT], qsq[QPT], mn[QPT];
    #pragma unroll
    for (int k = 0; k < QPT; ++k) {
        float xq = qp[k * qs3 + 0];
        float yq = qp[k * qs3 + 1];
        float zq = qp[k * qs3 + 2];
        nqx[k] = -2.0f * xq; nqy[k] = -2.0f * yq; nqz[k] = -2.0f * zq;
        qsq[k] = xq * xq + yq * yq + zq * zq;
        mn[k]  = BIGF;
    }

    __syncthreads();

    // 32 targets: per 2 targets & query -> 6 FMA + 1 v_min3_f32.
    #pragma unroll 2
    for (int j = 0; j < 32; j += 2) {
        float4 ta = lds[lbase + j + 0];           // broadcast: conflict-free
        float4 tb = lds[lbase + j + 1];
        #pragma unroll
        for (int k = 0; k < QPT; ++k) {
            float e0 = fmaf(nqx[k], ta.x,
                       fmaf(nqy[k], ta.y, fmaf(nqz[k], ta.z, ta.w)));
            float e1 = fmaf(nqx[k], tb.x,
                       fmaf(nqy[k], tb.y, fmaf(nqz[k], tb.z, tb.w)));
            mn[k] = fminf(fminf(mn[k], e0), e1);  // v_min3_f32
        }
    }

    #pragma unroll
    for (int k = 0; k < QPT; ++k)
        pbase[q0 + k * qstride] = qsq[k] + mn[k];
}

// 768 blocks: dir1 512 (4 lanes/query, 16 loads), dir2 256 (8 lanes, 32).
__global__ __launch_bounds__(256) void reduce_big(
    const float* __restrict__ pw, float* __restrict__ psum)
{
    const int blk = blockIdx.x, tid = threadIdx.x;
    float s;

    if (blk < 512) {                              // dir1: 64 chunks
        const int sub = tid & 3, qi = tid >> 2;   // 64 q/block
        const int qg = blk * 64 + qi;
        const int b = qg >> 13, ql = qg & 8191;
        const float* p = pw + (size_t)b * 64 * 8192 + ql;
        float m = BIGF;
        #pragma unroll
        for (int i = 0; i < 16; ++i)
            m = fminf(m, p[(sub * 16 + i) * 8192]);
        m = fminf(m, __shfl_xor(m, 1));
        m = fminf(m, __shfl_xor(m, 2));
        s = (sub == 0) ? fmaxf(m, 0.0f) : 0.0f;
    } else {                                      // dir2: 256 chunks
        const int sub = tid & 7, qi = tid >> 3;   // 32 q/block
        const int z = blk - 512;
        const int qg = z * 32 + qi;
        const int b = qg >> 11, ql = qg & 2047;
        const float* p = pw + P2B + (size_t)b * 256 * 2048 + ql;
        float m = BIGF;
        #pragma unroll
        for (int i = 0; i < 32; ++i)
            m = fminf(m, p[(sub * 32 + i) * 2048]);
        m = fminf(m, __shfl_xor(m, 1));
        m = fminf(m, __shfl_xor(m, 2));
        m = fminf(m, __shfl_xor(m, 4));
        s = (sub == 0) ? fmaxf(m, 0.0f) : 0.0f;
    }

    #pragma unroll
    for (int off = 32; off > 0; off >>= 1)
        s += __shfl_down(s, off);

    __shared__ float wsum[4];
    const int lane = tid & 63, w = tid >> 6;
    if (lane == 0) wsum[w] = s;
    __syncthreads();
    if (tid == 0) psum[blk] = (wsum[0] + wsum[1]) + (wsum[2] + wsum[3]);
}

// ---------------- SMALL path: R14 verbatim (proven 24.19) -----------------
__global__ __launch_bounds__(256) void chamfer_small(
    const float* __restrict__ shape, const float* __restrict__ skel,
    float* __restrict__ pw)
{
    const int b = blockIdx.y, tid = threadIdx.x;

    const float* q; float* pbase; const float* ssrc;
    int q0, qstride, lbase, scount;
    int x = blockIdx.x;
    if (x < 64) {                     // dir1
        const int qb = x >> 5, ch = x & 31;
        pbase   = pw + ((size_t)b * 32 + ch) * 8192;
        q0      = qb * 4096 + tid; qstride = 256;
        lbase   = 0;  scount = 64;
        ssrc    = skel + ((size_t)b * 2048 + ch * 64) * 3;
        q       = shape + (size_t)b * 8192 * 3;
    } else {                          // dir2
        const int z = x - 64, half = tid >> 7;
        const int ch = 2 * z + half;
        pbase   = pw + P2S + ((size_t)b * 128 + ch) * 2048;
        q0      = tid & 127; qstride = 128;
        lbase   = half * 64;  scount = 128;
        ssrc    = shape + ((size_t)b * 8192 + z * 128) * 3;
        q       = skel + (size_t)b * 2048 * 3;
    }

    __shared__ float4 lds[128];
    if (tid < scount) {
        float tx = ssrc[tid * 3 + 0], ty = ssrc[tid * 3 + 1], tz = ssrc[tid * 3 + 2];
        lds[tid] = make_float4(tx, ty, tz, tx * tx + ty * ty + tz * tz);
    }

    const float* qp = q + (size_t)q0 * 3;
    const int qs3 = qstride * 3;
    float nqx[QPT], nqy[QPT], nqz[QPT], qsq[QPT], mn[QPT];
    #pragma unroll
    for (int k = 0; k < QPT; ++k) {
        float xq = qp[k * qs3 + 0];
        float yq = qp[k * qs3 + 1];
        float zq = qp[k * qs3 + 2];
        nqx[k] = -2.0f * xq; nqy[k] = -2.0f * yq; nqz[k] = -2.0f * zq;
        qsq[k] = xq * xq + yq * yq + zq * zq;
        mn[k]  = BIGF;
    }

    __syncthreads();

    #pragma unroll 2
    for (int j = 0; j < 64; j += 2) {
        float4 ta = lds[lbase + j + 0];
        float4 tb = lds[lbase + j + 1];
        #pragma unroll
        for (int k = 0; k < QPT; ++k) {
            float e0 = fmaf(nqx[k], ta.x,
                       fmaf(nqy[k], ta.y, fmaf(nqz[k], ta.z, ta.w)));
            float e1 = fmaf(nqx[k], tb.x,
                       fmaf(nqy[k], tb.y, fmaf(nqz[k], tb.z, tb.w)));
            mn[k] = fminf(fminf(mn[k], e0), e1);
        }
    }

    #pragma unroll
    for (int k = 0; k < QPT; ++k)
        pbase[q0 + k * qstride] = qsq[k] + mn[k];
}

__global__ __launch_bounds__(256) void reduce_small(
    const float* __restrict__ pw, float* __restrict__ psum)
{
    const int blk = blockIdx.x, tid = threadIdx.x;
    const int sub = tid & 3, qi = tid >> 2;

    float m = BIGF;
    if (blk < 512) {
        const int b  = blk >> 7;
        const int ql = ((blk & 127) << 6) + qi;
        const float* p = pw + (size_t)b * 32 * 8192 + ql;
        #pragma unroll
        for (int i = 0; i < 8; ++i)
            m = fminf(m, p[(sub * 8 + i) * 8192]);
    } else {
        const int z  = blk - 512;
        const int b  = z >> 5;
        const int ql = ((z & 31) << 6) + qi;
        const float* p = pw + P2S + (size_t)b * 128 * 2048 + ql;
        #pragma unroll
        for (int i = 0; i < 32; ++i)
            m = fminf(m, p[(sub * 32 + i) * 2048]);
    }

    m = fminf(m, __shfl_xor(m, 1));
    m = fminf(m, __shfl_xor(m, 2));
    float s = (sub == 0) ? fmaxf(m, 0.0f) : 0.0f;

    #pragma unroll
    for (int off = 32; off > 0; off >>= 1)
        s += __shfl_down(s, off);

    __shared__ float wsum[4];
    const int lane = tid & 63, w = tid >> 6;
    if (lane == 0) wsum[w] = s;
    __syncthreads();
    if (tid == 0) psum[blk] = (wsum[0] + wsum[1]) + (wsum[2] + wsum[3]);
}

// ---------------- shared final: deterministic sum of n psums --------------
__global__ __launch_bounds__(256) void final_kernel(
    const float* __restrict__ psum, int n, float* __restrict__ out)
{
    float s = 0.0f;
    for (int i = threadIdx.x; i < n; i += 256)
        s += psum[i];

    #pragma unroll
    for (int off = 32; off > 0; off >>= 1)
        s += __shfl_down(s, off);

    __shared__ float wsum[4];
    const int lane = threadIdx.x & 63, w = threadIdx.x >> 6;
    if (lane == 0) wsum[w] = s;
    __syncthreads();
    if (threadIdx.x == 0)
        out[0] = ((wsum[0] + wsum[1]) + (wsum[2] + wsum[3])) * 1.0e-4f;
}

extern "C" void kernel_launch(void* const* d_in, const int* in_sizes, int n_in,
                              void* d_out, int out_size, void* d_ws, size_t ws_size,
                              hipStream_t stream) {
    const float* shape = (const float*)d_in[0];   // [4, 8192, 3]
    const float* skel  = (const float*)d_in[1];   // [4, 2048, 3]
    float* out         = (float*)d_out;           // scalar f32
    float* pw          = (float*)d_ws;

    const size_t need_big = (size_t)(PSB + RB_BIG) * sizeof(float); // ~16.8 MB

    if (ws_size >= need_big) {
        // BIG: 256 tiles/batch x 4 = 1024 blocks (4/CU, 16 waves/CU).
        chamfer_big<<<dim3(256, 4), 256, 0, stream>>>(shape, skel, pw);
        reduce_big<<<RB_BIG, 256, 0, stream>>>(pw, pw + PSB);
        final_kernel<<<1, 256, 0, stream>>>(pw + PSB, RB_BIG, out);
    } else {
        // SMALL (= R14): 128 tiles/batch x 4 = 512 blocks.
        chamfer_small<<<dim3(128, 4), 256, 0, stream>>>(shape, skel, pw);
        reduce_small<<<RB_SMALL, 256, 0, stream>>>(pw, pw + PSS);
        final_kernel<<<1, 256, 0, stream>>>(pw + PSS, RB_SMALL, out);
    }
}

// Round 16
// 24.842 us; speedup vs baseline: 1.2035x; 1.2035x over previous
//
#include <hip/hip_runtime.h>

// Bidirectional Chamfer loss, fused:
//   out = 1e-4 * ( sum_n min_m |shape[b,n]-skel[b,m]|^2
//                + sum_m min_n |skel[b,m]-shape[b,n]|^2 )
//
// R16: base = R14 (best 24.19: QPT=16, 512 blocks, LDS targets). Single
// change: WAVE DESYNC. R11 measured scan = VALU(6.0)+LDS(5.1) SUMMED even
// though LDS demand is only ~25-50% of VALU time -> convoy lockstep: all
// waves hit ds_read bursts together, the shared per-CU LDS pipe drains a
// 16-deep queue while VALUs idle, then all compute. Fix: each wave peels
// 8*(wid&3) targets in a rolled runtime-bound loop first, phase-shifting
// the waves so LDS bursts interleave under other waves' VALU. Same total
// work per thread; bit-identical result. Reduce/final = R7/R14 verbatim.

#define QPT    16     // query points per thread
#define BIGF   3.4e38f

// ws layout (floats):
//  dir1 partials [b][ch][q] : 4 x 32 x 8192 = 1,048,576
//  dir2 partials [b][ch][q] : 4 x 128 x 2048 = 1,048,576 (at P2_OFF)
//  psum: RBLOCKS floats at PSUM_OFF
#define P2_OFF   1048576
#define PSUM_OFF 2097152
#define RBLOCKS  640

// One pair of staged targets vs all QPT queries: 6 FMA + 1 v_min3_f32 each.
#define PAIR(J)                                                            \
    {                                                                      \
        float4 ta = lds[lbase + (J) + 0];                                  \
        float4 tb = lds[lbase + (J) + 1];                                  \
        _Pragma("unroll")                                                  \
        for (int k = 0; k < QPT; ++k) {                                    \
            float e0 = fmaf(nqx[k], ta.x,                                  \
                       fmaf(nqy[k], ta.y, fmaf(nqz[k], ta.z, ta.w)));      \
            float e1 = fmaf(nqx[k], tb.x,                                  \
                       fmaf(nqy[k], tb.y, fmaf(nqz[k], tb.z, tb.w)));      \
            mn[k] = fminf(fminf(mn[k], e0), e1);                           \
        }                                                                  \
    }

__global__ __launch_bounds__(256) void chamfer_kernel(
    const float* __restrict__ shape,  // [4, 8192, 3]
    const float* __restrict__ skel,   // [4, 2048, 3]
    float* __restrict__ pw)           // partial mins
{
    const int b   = blockIdx.y;
    const int tid = threadIdx.x;

    const float* q; float* pbase; const float* ssrc;
    int q0, qstride, lbase, scount;
    int x = blockIdx.x;
    if (x < 64) {                     // dir1: shape -> skel
        const int qb = x >> 5, ch = x & 31;
        pbase   = pw + ((size_t)b * 32 + ch) * 8192;
        q0      = qb * 4096 + tid;    // queries q0 + k*256, k<16
        qstride = 256;
        lbase   = 0;  scount = 64;
        ssrc    = skel + ((size_t)b * 2048 + ch * 64) * 3;
        q       = shape + (size_t)b * 8192 * 3;
    } else {                          // dir2: skel -> shape
        const int z = x - 64, half = tid >> 7;
        const int ch = 2 * z + half;
        pbase   = pw + P2_OFF + ((size_t)b * 128 + ch) * 2048;
        q0      = tid & 127;          // queries q0 + k*128, k<16
        qstride = 128;
        lbase   = half * 64;  scount = 128;
        ssrc    = shape + ((size_t)b * 8192 + z * 128) * 3;
        q       = skel + (size_t)b * 2048 * 3;
    }

    __shared__ float4 lds[128];

    // Stage targets as (x, y, z, |t|^2). dir1: 64, dir2: 128 (two chunks).
    if (tid < scount) {
        float tx = ssrc[tid * 3 + 0], ty = ssrc[tid * 3 + 1], tz = ssrc[tid * 3 + 2];
        lds[tid] = make_float4(tx, ty, tz, tx * tx + ty * ty + tz * tz);
    }

    // My QPT query points: precompute -2q and |q|^2.
    const float* qp = q + (size_t)q0 * 3;
    const int qs3 = qstride * 3;
    float nqx[QPT], nqy[QPT], nqz[QPT], qsq[QPT], mn[QPT];
    #pragma unroll
    for (int k = 0; k < QPT; ++k) {
        float xq = qp[k * qs3 + 0];
        float yq = qp[k * qs3 + 1];
        float zq = qp[k * qs3 + 2];
        nqx[k] = -2.0f * xq; nqy[k] = -2.0f * yq; nqz[k] = -2.0f * zq;
        qsq[k] = xq * xq + yq * yq + zq * zq;
        mn[k]  = BIGF;
    }

    __syncthreads();

    // Wave-desync peel: wave w (0..3) processes 8*w targets in a ROLLED
    // runtime-bound loop, phase-shifting the waves; the main loop then
    // runs with waves offset so LDS bursts hide under other waves' VALU.
    const int P = ((tid >> 6) & 3) * 8;
    #pragma unroll 1
    for (int j = 0; j < P; j += 2)
        PAIR(j);

    #pragma unroll 2
    for (int j = P; j < 64; j += 2)
        PAIR(j);

    // One coalesced store per (query, chunk) partial — no atomics.
    #pragma unroll
    for (int k = 0; k < QPT; ++k)
        pbase[q0 + k * qstride] = qsq[k] + mn[k];
}

// 640 blocks: 64 queries/block, 4 lanes per query split over chunks.
// Blocks 0..511 = dir1 (32 chunks), 512..639 = dir2 (128 chunks).
__global__ __launch_bounds__(256) void reduce_kernel(
    const float* __restrict__ pw, float* __restrict__ psum)
{
    const int blk = blockIdx.x, tid = threadIdx.x;
    const int sub = tid & 3, qi = tid >> 2;       // 4 lanes per query

    float m = BIGF;
    if (blk < 512) {                              // dir1: 8 loads/lane
        const int b  = blk >> 7;
        const int ql = ((blk & 127) << 6) + qi;
        const float* p = pw + (size_t)b * 32 * 8192 + ql;
        #pragma unroll
        for (int i = 0; i < 8; ++i)
            m = fminf(m, p[(sub * 8 + i) * 8192]);
    } else {                                      // dir2: 32 loads/lane
        const int z  = blk - 512;
        const int b  = z >> 5;
        const int ql = ((z & 31) << 6) + qi;
        const float* p = pw + P2_OFF + (size_t)b * 128 * 2048 + ql;
        #pragma unroll
        for (int i = 0; i < 32; ++i)
            m = fminf(m, p[(sub * 32 + i) * 2048]);
    }

    // Min across the 4-lane group, clamp, keep one copy.
    m = fminf(m, __shfl_xor(m, 1));
    m = fminf(m, __shfl_xor(m, 2));
    float s = (sub == 0) ? fmaxf(m, 0.0f) : 0.0f;

    // Wave + block sum.
    #pragma unroll
    for (int off = 32; off > 0; off >>= 1)
        s += __shfl_down(s, off);

    __shared__ float wsum[4];
    const int lane = tid & 63, w = tid >> 6;
    if (lane == 0) wsum[w] = s;
    __syncthreads();
    if (tid == 0) psum[blk] = (wsum[0] + wsum[1]) + (wsum[2] + wsum[3]);
}

__global__ __launch_bounds__(256) void final_kernel(
    const float* __restrict__ psum, float* __restrict__ out)
{
    float s = psum[threadIdx.x] + psum[threadIdx.x + 256];
    if (threadIdx.x < 128) s += psum[threadIdx.x + 512];

    #pragma unroll
    for (int off = 32; off > 0; off >>= 1)
        s += __shfl_down(s, off);

    __shared__ float wsum[4];
    const int lane = threadIdx.x & 63, w = threadIdx.x >> 6;
    if (lane == 0) wsum[w] = s;
    __syncthreads();
    if (threadIdx.x == 0)
        out[0] = ((wsum[0] + wsum[1]) + (wsum[2] + wsum[3])) * 1.0e-4f;
}

extern "C" void kernel_launch(void* const* d_in, const int* in_sizes, int n_in,
                              void* d_out, int out_size, void* d_ws, size_t ws_size,
                              hipStream_t stream) {
    const float* shape = (const float*)d_in[0];   // [4, 8192, 3]
    const float* skel  = (const float*)d_in[1];   // [4, 2048, 3]
    float* out         = (float*)d_out;           // scalar f32
    float* pw          = (float*)d_ws;

    // 128 tiles/batch x 4 batches = 512 blocks (2/CU, 8 waves/CU).
    chamfer_kernel<<<dim3(128, 4), 256, 0, stream>>>(shape, skel, pw);

    // 640 blocks, then tiny deterministic final sum.
    reduce_kernel<<<RBLOCKS, 256, 0, stream>>>(pw, pw + PSUM_OFF);
    final_kernel<<<1, 256, 0, stream>>>(pw + PSUM_OFF, out);
}